// Round 17
// baseline (283.276 us; speedup 1.0000x reference)
//
#include <hip/hip_runtime.h>

using short8 = __attribute__((ext_vector_type(8))) short;
using f32x4  = __attribute__((ext_vector_type(4))) float;

__device__ __forceinline__ short f2bf(float f){
  unsigned u = __float_as_uint(f);
  unsigned r = (u + 0x7FFFu + ((u >> 16) & 1u)) >> 16;
  return (short)r;
}
__device__ __forceinline__ float sget(float x){   // force wave-uniform value into SGPR
  return __uint_as_float(__builtin_amdgcn_readfirstlane(__float_as_uint(x)));
}
__device__ __forceinline__ unsigned cvtpk_bf16(float lo, float hi){
  unsigned d;
  asm("v_cvt_pk_bf16_f32 %0, %1, %2" : "=v"(d) : "v"(lo), "v"(hi));
  return d;
}
__device__ __forceinline__ void async_cp16(short* lds, const short* g){
  __builtin_amdgcn_global_load_lds((const __attribute__((address_space(1))) unsigned int*)g,
                                   (__attribute__((address_space(3))) unsigned int*)lds,
                                   16, 0, 0);
}

// ---------------- merged depthwise 3x3 (dw1: stride1 q | dw2: stride2 k,v) ----------------
__global__ __launch_bounds__(384) void k_dw(const float* __restrict__ inq, const float* __restrict__ inkv,
                                            const float* __restrict__ wq, const float* __restrict__ wk,
                                            const float* __restrict__ wv,
                                            short* __restrict__ dqb, short* __restrict__ dkb,
                                            short* __restrict__ dvb, float2* __restrict__ partq,
                                            float2* __restrict__ partk, float2* __restrict__ partv){
  __shared__ float red[4][384];
  int t = threadIdx.x;
  int c = t % 192, strip = t / 192;
  if(blockIdx.x < 896){
    int bid = blockIdx.x; int b = bid / 56, oh = bid % 56;
    float w[9];
#pragma unroll
    for(int i=0;i<9;i++) w[i] = wq[i*192 + c];
    const float* inb = inq + (size_t)b*56*56*192;
    const float* rp[3]; bool rv[3];
#pragma unroll
    for(int kh=0;kh<3;kh++){
      int ih = oh + kh - 1;
      rv[kh] = (ih >= 0 && ih < 56);
      rp[kh] = inb + (size_t)(rv[kh] ? ih : 0)*56*192 + c;
    }
    auto ldc = [&](int kh, int iw)->float{
      return (rv[kh] && iw >= 0 && iw < 56) ? rp[kh][iw*192] : 0.f;
    };
    int ow0 = strip*28;
    float x0[3], x1[3];
#pragma unroll
    for(int kh=0;kh<3;kh++){ x0[kh] = ldc(kh, ow0-1); x1[kh] = ldc(kh, ow0); }
    float lsum = 0.f, lsq = 0.f;
    size_t orow = ((size_t)b*3136 + (size_t)oh*56)*192;
#pragma unroll 1
    for(int j=0;j<28;j++){
      int ow = ow0 + j;
      float x2[3];
#pragma unroll
      for(int kh=0;kh<3;kh++) x2[kh] = ldc(kh, ow+1);
      float acc = 0.f;
#pragma unroll
      for(int kh=0;kh<3;kh++){
        acc = fmaf(x0[kh], w[kh*3+0], acc);
        acc = fmaf(x1[kh], w[kh*3+1], acc);
        acc = fmaf(x2[kh], w[kh*3+2], acc);
      }
      dqb[orow + (size_t)ow*192 + c] = f2bf(acc);
      lsum += acc; lsq = fmaf(acc, acc, lsq);
#pragma unroll
      for(int kh=0;kh<3;kh++){ x0[kh] = x1[kh]; x1[kh] = x2[kh]; }
    }
    red[0][t] = lsum; red[1][t] = lsq;
    __syncthreads();
    if(t < 192){
      float2 o; o.x = lsum + red[0][t+192]; o.y = lsq + red[1][t+192];
      partq[(size_t)bid*192 + t] = o;
    }
  } else {
    int bid = blockIdx.x - 896; int b = bid / 28, oh = bid % 28;
    float wkr[9], wvr[9];
#pragma unroll
    for(int i=0;i<9;i++){ wkr[i] = wk[i*192 + c]; wvr[i] = wv[i*192 + c]; }
    const float* inb = inkv + (size_t)b*56*56*192;
    const float* rp[3]; bool rv[3];
#pragma unroll
    for(int kh=0;kh<3;kh++){
      int ih = 2*oh + kh;
      rv[kh] = (ih < 56);
      rp[kh] = inb + (size_t)(rv[kh] ? ih : 0)*56*192 + c;
    }
    auto ldc = [&](int kh, int iw)->float{
      return (rv[kh] && iw < 56) ? rp[kh][iw*192] : 0.f;
    };
    int ow0 = strip*14;
    float xp[3];
#pragma unroll
    for(int kh=0;kh<3;kh++) xp[kh] = ldc(kh, 2*ow0);
    float ksum=0.f, ksq=0.f, vsum=0.f, vsq=0.f;
    size_t orow = ((size_t)b*784 + (size_t)oh*28)*192;
#pragma unroll 1
    for(int j=0;j<14;j++){
      int ow = ow0 + j;
      float xm[3], xn[3];
#pragma unroll
      for(int kh=0;kh<3;kh++){ xm[kh] = ldc(kh, 2*ow+1); xn[kh] = ldc(kh, 2*ow+2); }
      float ak = 0.f, av = 0.f;
#pragma unroll
      for(int kh=0;kh<3;kh++){
        ak = fmaf(xp[kh], wkr[kh*3+0], ak); ak = fmaf(xm[kh], wkr[kh*3+1], ak); ak = fmaf(xn[kh], wkr[kh*3+2], ak);
        av = fmaf(xp[kh], wvr[kh*3+0], av); av = fmaf(xm[kh], wvr[kh*3+1], av); av = fmaf(xn[kh], wvr[kh*3+2], av);
      }
      dkb[orow + (size_t)ow*192 + c] = f2bf(ak);
      dvb[orow + (size_t)ow*192 + c] = f2bf(av);
      ksum += ak; ksq = fmaf(ak, ak, ksq);
      vsum += av; vsq = fmaf(av, av, vsq);
#pragma unroll
      for(int kh=0;kh<3;kh++) xp[kh] = xn[kh];
    }
    red[0][t]=ksum; red[1][t]=ksq; red[2][t]=vsum; red[3][t]=vsq;
    __syncthreads();
    if(t < 192){
      float2 a; a.x = ksum + red[0][t+192]; a.y = ksq + red[1][t+192];
      partk[(size_t)bid*192 + t] = a;
      float2 o; o.x = vsum + red[2][t+192]; o.y = vsq + red[3][t+192];
      partv[(size_t)bid*192 + t] = o;
    }
  }
}

// ---------------- stage-1 reduce of stats partials ----------------
__global__ __launch_bounds__(192) void k_red(const float2* __restrict__ pq, const float2* __restrict__ pk,
                                             const float2* __restrict__ pv, float2* __restrict__ oq,
                                             float2* __restrict__ ok2, float2* __restrict__ ov2){
  int blk = blockIdx.x, t = threadIdx.x;
  const float2* src; float2* dst;
  if(blk < 8){ src = pq + (size_t)blk*112*192;      dst = oq  + (size_t)blk*192; }
  else if(blk < 12){ src = pk + (size_t)(blk-8)*112*192;  dst = ok2 + (size_t)(blk-8)*192; }
  else { src = pv + (size_t)(blk-12)*112*192; dst = ov2 + (size_t)(blk-12)*192; }
  float s=0.f, q=0.f;
#pragma unroll 8
  for(int i=0;i<112;i++){ float2 v = src[(size_t)i*192 + t]; s += v.x; q += v.y; }
  float2 o; o.x=s; o.y=q; dst[t] = o;
}

// ---------------- finalize stats; fold BN + scale into transposed bf16 weights ----------------
__global__ __launch_bounds__(192) void k_fin(const float2* __restrict__ pq, const float2* __restrict__ pk,
                                             const float2* __restrict__ pv,
                                             const float* __restrict__ sq, const float* __restrict__ oq,
                                             const float* __restrict__ sk, const float* __restrict__ ok,
                                             const float* __restrict__ sv, const float* __restrict__ ov,
                                             const float* __restrict__ pwq, const float* __restrict__ pwk,
                                             const float* __restrict__ pwv, const float* __restrict__ wout,
                                             short* __restrict__ Wt, float* __restrict__ bias){
  int p = blockIdx.x, t = threadIdx.x;
  __shared__ float aS[192], bS[192];
  if(p < 3){
    const float2* part = (p==0)?pq:((p==1)?pk:pv);
    int nb = (p==0)?8:4;
    float N = (p==0)?50176.f:12544.f;
    const float* sc = (p==0)?sq:((p==1)?sk:sv);
    const float* of = (p==0)?oq:((p==1)?ok:ov);
    float s=0.f, q2=0.f;
#pragma unroll
    for(int i=0;i<8;i++){ if(i<nb){ float2 v = part[(size_t)i*192 + t]; s += v.x; q2 += v.y; } }
    float mean = s / N;
    float var  = q2 / N - mean*mean;
    float a  = rsqrtf(var + 1e-5f) * sc[t];
    float bv = of[t] - mean*a;
    aS[t] = a; bS[t] = bv;
    __syncthreads();
    const float* pw = (p==0)?pwq:((p==1)?pwk:pwv);
    float qs = (p==0) ? 0.125f : 1.0f;   // fold 1/sqrt(64) into q
    float bacc = 0.f;
    for(int cc=0; cc<192; cc++){
      float wv_ = pw[cc*192 + t];
      bacc = fmaf(bS[cc], wv_, bacc);
      Wt[((size_t)p*192 + t)*192 + cc] = f2bf(aS[cc]*wv_*qs);
    }
    bias[p*192 + t] = bacc * qs;
  } else {
    for(int cc=0; cc<192; cc++) Wt[((size_t)3*192 + t)*192 + cc] = f2bf(wout[cc*192 + t]);
    bias[3*192 + t] = 0.f;
  }
}

// ---------------- K/V pointwise GEMM writing DMA-ready tiled layouts ----------------
// K tile t (32 k-rows): [chunk c24][row r32][8 shorts] -> elem(r,col) at c*256+r*8+(col&7), c=col>>3
// V tile t: [kchunk kc4][col192][8 shorts] -> elem(col,kk) at kc*1536+col*8+(kk&7), kc=(kk&31)>>3
__global__ __launch_bounds__(256) void k_kv(const short* __restrict__ dkb, const short* __restrict__ dvb,
                                            const short* __restrict__ Wt, const float* __restrict__ bias,
                                            short* __restrict__ kbuf, short* __restrict__ vtb){
  int blk = blockIdx.x;
  bool isV = blk >= 208;
  int pb = isV ? blk - 208 : blk;
  int w = threadIdx.x >> 6, L = threadIdx.x & 63, l16 = L & 15, h4 = L >> 4;
  int row0 = pb*64 + w*16;
  int b = row0 / 832, kk0 = row0 - b*832;
  const short* A = isV ? dvb : dkb;
  const short* Wp = Wt + (isV ? 2 : 1)*36864;
  const float* bp = bias + (isV ? 2 : 1)*192;
  int kkA = kk0 + l16; if(kkA > 783) kkA = 783;
  short8 af[6];
  const short8* arow = (const short8*)(A + (size_t)(b*784 + kkA)*192);
#pragma unroll
  for(int kf=0;kf<6;kf++) af[kf] = arow[kf*4 + h4];
  short* obase = (isV ? vtb : kbuf) + (size_t)b*26*6144;
#pragma unroll
  for(int nt=0;nt<12;nt++){
    f32x4 acc = f32x4{0.f,0.f,0.f,0.f};
    const short8* wrow = (const short8*)(Wp + (size_t)(nt*16 + l16)*192);
#pragma unroll
    for(int kf=0;kf<6;kf++)
      acc = __builtin_amdgcn_mfma_f32_16x16x32_bf16(af[kf], wrow[kf*4 + h4], acc, 0,0,0);
    int col = nt*16 + l16;
    float bv = bp[col];
#pragma unroll
    for(int r=0;r<4;r++){
      int kk = kk0 + h4*4 + r;
      float v = (kk < 784) ? (acc[r] + bv) : 0.f;
      int t = kk >> 5, rr = kk & 31;
      if(!isV) obase[(size_t)t*6144 + (col>>3)*256 + rr*8 + (col&7)] = f2bf(v);
      else     obase[(size_t)t*6144 + (rr>>3)*1536 + col*8 + (rr&7)] = f2bf(v);
    }
  }
}

// ---------------- fused TWO-PASS talking-heads attention ----------------
// Pass A: QK+premix+exp2 -> Z (K-only DMA dbuf, no sP/PV). invZ via shfl.
// Pass B: QK again -> normalize+postmix in score domain -> P~[gp] -> PV (12 MFMA, V DMA dbuf).
// Accumulator U[3][4] = 48 regs; arch+acc <= 256 -> 2 waves/SIMD (vs 1 for single-pass).
__global__ __launch_bounds__(256, 2) void k_attn(const short* __restrict__ dq, const short* __restrict__ Wt,
                                                 const float* __restrict__ bias,
                                                 const short* __restrict__ kb, const short* __restrict__ vt,
                                                 const float* __restrict__ pre, const float* __restrict__ post,
                                                 float* __restrict__ outp){
  __shared__ __align__(16) short sS[32256];  // 64512 B: sK0|sK1|sV0|sV1 | sP
  short* sKb = sS;              // 2 x 6144
  short* sVb = sS + 12288;      // 2 x 6144
  short* sP  = sS + 24576;      // [4 w][3 gp][16 q][40]
  int bid = blockIdx.x;
  int b  = ((bid & 7) << 1) | ((bid >> 3) & 1);   // XCD-aware: 2 b's per XCD
  int lt = bid >> 4;
  int tid = threadIdx.x; int w = tid >> 6, lane = tid & 63, l16 = lane & 15, h4 = lane >> 4;
  int lw = lt*64 + w*16;
  short* sScr = sS + w*3200;    // per-wave [16][200] prologue/epilogue scratch (overlaps bufs; barriered)

  // ---- prologue: q = dq @ WtQ^T + biasQ (BN + 1/8 folded), transpose via LDS ----
  {
    short8 af[6];
    const short8* arow = (const short8*)(dq + ((size_t)b*3136 + lw + l16)*192);
#pragma unroll
    for(int kf=0;kf<6;kf++) af[kf] = arow[kf*4 + h4];
#pragma unroll 1
    for(int nt=0;nt<12;nt++){
      f32x4 acc = f32x4{0.f,0.f,0.f,0.f};
      const short8* wrow = (const short8*)(Wt + (size_t)(nt*16 + l16)*192);
#pragma unroll
      for(int kf=0;kf<6;kf++)
        acc = __builtin_amdgcn_mfma_f32_16x16x32_bf16(af[kf], wrow[kf*4 + h4], acc, 0,0,0);
      float bv = bias[nt*16 + l16];
#pragma unroll
      for(int r=0;r<4;r++) sScr[(h4*4+r)*200 + nt*16 + l16] = f2bf(acc[r] + bv);
    }
  }
  short8 qf[3][2];
#pragma unroll
  for(int h=0;h<3;h++)
#pragma unroll
    for(int kf=0;kf<2;kf++) qf[h][kf] = *(const short8*)&sScr[l16*200 + h*64 + kf*32 + h4*8];

  float pm[3][3];
#pragma unroll
  for(int h=0;h<3;h++)
#pragma unroll
    for(int g=0;g<3;g++) pm[h][g] = sget(pre[h*3+g]) * 1.44269504f;   // fold log2(e)

  const short* kgb = kb + (size_t)b*26*6144;
  const short* vgb = vt + (size_t)b*26*6144;
  int soff = w*1536;            // wave's slice of a 6144-short tile

  auto stageK = [&](int t){
    short* kl = sKb + (t&1)*6144 + soff;
    const short* kg = kgb + (size_t)t*6144 + soff + lane*8;
#pragma unroll
    for(int j=0;j<3;j++) async_cp16(kl + j*512, kg + j*512);
  };
  auto stageKV = [&](int t){
    short* kl = sKb + (t&1)*6144 + soff;
    short* vl = sVb + (t&1)*6144 + soff;
    const short* kg = kgb + (size_t)t*6144 + soff + lane*8;
    const short* vg = vgb + (size_t)t*6144 + soff + lane*8;
#pragma unroll
    for(int j=0;j<3;j++){
      async_cp16(kl + j*512, kg + j*512);
      async_cp16(vl + j*512, vg + j*512);
    }
  };

  float Zp[3] = {0.f, 0.f, 0.f};
  __syncthreads();              // prologue scratch reads done before DMA lands
  stageK(0);
  __syncthreads();              // vmcnt drained: tile 0 ready

  // ================= pass A: accumulate Z (no sP, no V, no PV) =================
#pragma unroll 1
  for(int ks=0; ks<25; ks++){
    if(ks < 24) stageK(ks+1);
    const short* sKc = sKb + (ks&1)*6144;
#pragma unroll
    for(int nt=0;nt<2;nt++){
      f32x4 a3[3];
#pragma unroll
      for(int h=0;h<3;h++) a3[h] = f32x4{0.f,0.f,0.f,0.f};
      __builtin_amdgcn_s_setprio(1);
#pragma unroll
      for(int h=0;h<3;h++)
#pragma unroll
        for(int kf=0;kf<2;kf++){
          short8 bk = *(const short8*)&sKc[(h*8 + kf*4 + h4)*256 + (nt*16 + l16)*8];
          a3[h] = __builtin_amdgcn_mfma_f32_16x16x32_bf16(bk, qf[h][kf], a3[h], 0,0,0);
        }
      __builtin_amdgcn_s_setprio(0);
      bool zok = (ks < 24) || (nt == 0);        // only (ks==24,nt==1) holds padded k
#pragma unroll
      for(int g=0;g<3;g++){
        float e0 = exp2f(fmaf(pm[0][g], a3[0][0], fmaf(pm[1][g], a3[1][0], pm[2][g]*a3[2][0])));
        float e1 = exp2f(fmaf(pm[0][g], a3[0][1], fmaf(pm[1][g], a3[1][1], pm[2][g]*a3[2][1])));
        float e2 = exp2f(fmaf(pm[0][g], a3[0][2], fmaf(pm[1][g], a3[1][2], pm[2][g]*a3[2][2])));
        float e3 = exp2f(fmaf(pm[0][g], a3[0][3], fmaf(pm[1][g], a3[1][3], pm[2][g]*a3[2][3])));
        if(zok) Zp[g] += (e0 + e1) + (e2 + e3);
      }
    }
    __syncthreads();
  }

  // invZ for this lane's q-row (q = l16), per premix head g
  float izq[3];
#pragma unroll
  for(int g=0;g<3;g++){
    float z = Zp[g];
    z += __shfl_xor(z, 16); z += __shfl_xor(z, 32);
    izq[g] = 1.f / z;
  }
  float po[3][3];
#pragma unroll
  for(int g=0;g<3;g++)
#pragma unroll
    for(int gp=0;gp<3;gp++) po[g][gp] = sget(post[g*3+gp]);

  f32x4 U[3][4];
#pragma unroll
  for(int gp=0;gp<3;gp++)
#pragma unroll
    for(int nt=0;nt<4;nt++) U[gp][nt] = f32x4{0.f,0.f,0.f,0.f};

  stageKV(0);                   // all waves past pass-A final barrier
  __syncthreads();

  // ================= pass B: normalized post-mixed P~, PV (12 MFMA/iter) =================
  int sPw = w*1920;
#pragma unroll 1
  for(int ks=0; ks<25; ks++){
    if(ks < 24) stageKV(ks+1);
    const short* sKc = sKb + (ks&1)*6144;
    const short* sVc = sVb + (ks&1)*6144;
#pragma unroll
    for(int nt=0;nt<2;nt++){
      f32x4 a3[3];
#pragma unroll
      for(int h=0;h<3;h++) a3[h] = f32x4{0.f,0.f,0.f,0.f};
      __builtin_amdgcn_s_setprio(1);
#pragma unroll
      for(int h=0;h<3;h++)
#pragma unroll
        for(int kf=0;kf<2;kf++){
          short8 bk = *(const short8*)&sKc[(h*8 + kf*4 + h4)*256 + (nt*16 + l16)*8];
          a3[h] = __builtin_amdgcn_mfma_f32_16x16x32_bf16(bk, qf[h][kf], a3[h], 0,0,0);
        }
      __builtin_amdgcn_s_setprio(0);
      float pn[3][4];
#pragma unroll
      for(int g=0;g<3;g++)
#pragma unroll
        for(int r=0;r<4;r++){
          float sm = fmaf(pm[0][g], a3[0][r], fmaf(pm[1][g], a3[1][r], pm[2][g]*a3[2][r]));
          pn[g][r] = exp2f(sm) * izq[g];
        }
      // padded k rows (ks==24,nt==1): V rows are zero -> their PV contribution nulls
#pragma unroll
      for(int gp=0;gp<3;gp++){
        float w0 = fmaf(po[0][gp], pn[0][0], fmaf(po[1][gp], pn[1][0], po[2][gp]*pn[2][0]));
        float w1 = fmaf(po[0][gp], pn[0][1], fmaf(po[1][gp], pn[1][1], po[2][gp]*pn[2][1]));
        float w2 = fmaf(po[0][gp], pn[0][2], fmaf(po[1][gp], pn[1][2], po[2][gp]*pn[2][2]));
        float w3 = fmaf(po[0][gp], pn[0][3], fmaf(po[1][gp], pn[1][3], po[2][gp]*pn[2][3]));
        uint2 dw; dw.x = cvtpk_bf16(w0, w1); dw.y = cvtpk_bf16(w2, w3);
        *(uint2*)&sP[sPw + gp*640 + l16*40 + nt*16 + h4*4] = dw;
      }
    }
    // ---- PV: P~[gp] (LDS, within-wave RAW) x V (LDS dbuf) -> 12 MFMA ----
    short8 pa[3];
#pragma unroll
    for(int gp=0;gp<3;gp++) pa[gp] = *(const short8*)&sP[sPw + gp*640 + l16*40 + h4*8];
    __builtin_amdgcn_s_setprio(1);
#pragma unroll
    for(int gp=0;gp<3;gp++)
#pragma unroll
      for(int nt=0;nt<4;nt++){
        short8 vb = *(const short8*)&sVc[h4*1536 + (gp*64 + nt*16 + l16)*8];
        U[gp][nt] = __builtin_amdgcn_mfma_f32_16x16x32_bf16(pa[gp], vb, U[gp][nt], 0,0,0);
      }
    __builtin_amdgcn_s_setprio(0);
    __syncthreads();            // DMAs landed; all waves done with slot ks&1
  }

  // ---- epilogue: U is final s (normalized+mixed); bf16 -> scratch, @ Wout, write f32 ----
#pragma unroll
  for(int gp=0;gp<3;gp++)
#pragma unroll
    for(int nt=0;nt<4;nt++)
#pragma unroll
      for(int r=0;r<4;r++)
        sScr[(h4*4+r)*200 + gp*64 + nt*16 + l16] = f2bf(U[gp][nt][r]);
  short8 uf[6];
#pragma unroll
  for(int kf=0;kf<6;kf++) uf[kf] = *(const short8*)&sScr[l16*200 + kf*32 + h4*8];
  const short* W3 = Wt + 3*36864;
#pragma unroll 1
  for(int nt=0;nt<12;nt++){
    f32x4 acc = f32x4{0.f,0.f,0.f,0.f};
    const short8* wrow = (const short8*)(W3 + (size_t)(nt*16 + l16)*192);
#pragma unroll
    for(int kf=0;kf<6;kf++)
      acc = __builtin_amdgcn_mfma_f32_16x16x32_bf16(uf[kf], wrow[kf*4 + h4], acc, 0,0,0);
#pragma unroll
    for(int r=0;r<4;r++)
      outp[((size_t)b*3136 + lw + h4*4 + r)*192 + nt*16 + l16] = acc[r];
  }
}

extern "C" void kernel_launch(void* const* d_in, const int* in_sizes, int n_in,
                              void* d_out, int out_size, void* d_ws, size_t ws_size,
                              hipStream_t stream){
  (void)in_sizes; (void)n_in; (void)out_size; (void)ws_size;
  const float* inq  = (const float*)d_in[0];
  const float* inkv = (const float*)d_in[1];
  const float* dwq  = (const float*)d_in[2];
  const float* dwk  = (const float*)d_in[3];
  const float* dwv  = (const float*)d_in[4];
  const float* scq  = (const float*)d_in[5];  const float* ofq = (const float*)d_in[6];
  const float* sck  = (const float*)d_in[7];  const float* ofk = (const float*)d_in[8];
  const float* scv  = (const float*)d_in[9];  const float* ofv = (const float*)d_in[10];
  const float* pwq  = (const float*)d_in[11];
  const float* pwk  = (const float*)d_in[12];
  const float* pwv  = (const float*)d_in[13];
  const float* pre  = (const float*)d_in[14];
  const float* post = (const float*)d_in[15];
  const float* wout = (const float*)d_in[16];

  char* ws = (char*)d_ws;
  size_t off = 0;
  auto alloc = [&](size_t bytes)->void*{ void* p = ws + off; off += (bytes + 255) & ~(size_t)255; return p; };
  short*  dqb  = (short*) alloc(50176ull*192*2);
  short*  dkb  = (short*) alloc(12544ull*192*2);
  short*  dvb  = (short*) alloc(12544ull*192*2);
  short*  kbuf = (short*) alloc(16ull*26*6144*2);
  short*  vtb  = (short*) alloc(16ull*26*6144*2);
  float2* pq   = (float2*)alloc(896ull*192*sizeof(float2));
  float2* pk   = (float2*)alloc(448ull*192*sizeof(float2));
  float2* pv   = (float2*)alloc(448ull*192*sizeof(float2));
  float2* pq2  = (float2*)alloc(8ull*192*sizeof(float2));
  float2* pk2  = (float2*)alloc(4ull*192*sizeof(float2));
  float2* pv2  = (float2*)alloc(4ull*192*sizeof(float2));
  short*  Wt   = (short*) alloc(4ull*192*192*2);
  float*  bias = (float*) alloc(4ull*192*4);

  k_dw<<<1344, 384, 0, stream>>>(inq, inkv, dwq, dwk, dwv, dqb, dkb, dvb, pq, pk, pv);
  k_red<<<16, 192, 0, stream>>>(pq, pk, pv, pq2, pk2, pv2);
  k_fin<<<4, 192, 0, stream>>>(pq2, pk2, pv2, scq, ofq, sck, ofk, scv, ofv, pwq, pwk, pwv, wout, Wt, bias);
  k_kv<<<416, 256, 0, stream>>>(dkb, dvb, Wt, bias, kbuf, vtb);
  k_attn<<<784, 256, 0, stream>>>(dqb, Wt, bias, kbuf, vtb, pre, post, (float*)d_out);
}

// Round 18
// 233.964 us; speedup vs baseline: 1.2108x; 1.2108x over previous
//
#include <hip/hip_runtime.h>

using short8 = __attribute__((ext_vector_type(8))) short;
using f32x4  = __attribute__((ext_vector_type(4))) float;

__device__ __forceinline__ short f2bf(float f){
  unsigned u = __float_as_uint(f);
  unsigned r = (u + 0x7FFFu + ((u >> 16) & 1u)) >> 16;
  return (short)r;
}
__device__ __forceinline__ float sget(float x){   // force wave-uniform value into SGPR
  return __uint_as_float(__builtin_amdgcn_readfirstlane(__float_as_uint(x)));
}
__device__ __forceinline__ unsigned cvtpk_bf16(float lo, float hi){
  unsigned d;
  asm("v_cvt_pk_bf16_f32 %0, %1, %2" : "=v"(d) : "v"(lo), "v"(hi));
  return d;
}
__device__ __forceinline__ void async_cp16(short* lds, const short* g){
  __builtin_amdgcn_global_load_lds((const __attribute__((address_space(1))) unsigned int*)g,
                                   (__attribute__((address_space(3))) unsigned int*)lds,
                                   16, 0, 0);
}

// ---------------- merged depthwise 3x3 (dw1: stride1 q | dw2: stride2 k,v) ----------------
__global__ __launch_bounds__(384) void k_dw(const float* __restrict__ inq, const float* __restrict__ inkv,
                                            const float* __restrict__ wq, const float* __restrict__ wk,
                                            const float* __restrict__ wv,
                                            short* __restrict__ dqb, short* __restrict__ dkb,
                                            short* __restrict__ dvb, float2* __restrict__ partq,
                                            float2* __restrict__ partk, float2* __restrict__ partv){
  __shared__ float red[4][384];
  int t = threadIdx.x;
  int c = t % 192, strip = t / 192;
  if(blockIdx.x < 896){
    int bid = blockIdx.x; int b = bid / 56, oh = bid % 56;
    float w[9];
#pragma unroll
    for(int i=0;i<9;i++) w[i] = wq[i*192 + c];
    const float* inb = inq + (size_t)b*56*56*192;
    const float* rp[3]; bool rv[3];
#pragma unroll
    for(int kh=0;kh<3;kh++){
      int ih = oh + kh - 1;
      rv[kh] = (ih >= 0 && ih < 56);
      rp[kh] = inb + (size_t)(rv[kh] ? ih : 0)*56*192 + c;
    }
    auto ldc = [&](int kh, int iw)->float{
      return (rv[kh] && iw >= 0 && iw < 56) ? rp[kh][iw*192] : 0.f;
    };
    int ow0 = strip*28;
    float x0[3], x1[3];
#pragma unroll
    for(int kh=0;kh<3;kh++){ x0[kh] = ldc(kh, ow0-1); x1[kh] = ldc(kh, ow0); }
    float lsum = 0.f, lsq = 0.f;
    size_t orow = ((size_t)b*3136 + (size_t)oh*56)*192;
#pragma unroll 1
    for(int j=0;j<28;j++){
      int ow = ow0 + j;
      float x2[3];
#pragma unroll
      for(int kh=0;kh<3;kh++) x2[kh] = ldc(kh, ow+1);
      float acc = 0.f;
#pragma unroll
      for(int kh=0;kh<3;kh++){
        acc = fmaf(x0[kh], w[kh*3+0], acc);
        acc = fmaf(x1[kh], w[kh*3+1], acc);
        acc = fmaf(x2[kh], w[kh*3+2], acc);
      }
      dqb[orow + (size_t)ow*192 + c] = f2bf(acc);
      lsum += acc; lsq = fmaf(acc, acc, lsq);
#pragma unroll
      for(int kh=0;kh<3;kh++){ x0[kh] = x1[kh]; x1[kh] = x2[kh]; }
    }
    red[0][t] = lsum; red[1][t] = lsq;
    __syncthreads();
    if(t < 192){
      float2 o; o.x = lsum + red[0][t+192]; o.y = lsq + red[1][t+192];
      partq[(size_t)bid*192 + t] = o;
    }
  } else {
    int bid = blockIdx.x - 896; int b = bid / 28, oh = bid % 28;
    float wkr[9], wvr[9];
#pragma unroll
    for(int i=0;i<9;i++){ wkr[i] = wk[i*192 + c]; wvr[i] = wv[i*192 + c]; }
    const float* inb = inkv + (size_t)b*56*56*192;
    const float* rp[3]; bool rv[3];
#pragma unroll
    for(int kh=0;kh<3;kh++){
      int ih = 2*oh + kh;
      rv[kh] = (ih < 56);
      rp[kh] = inb + (size_t)(rv[kh] ? ih : 0)*56*192 + c;
    }
    auto ldc = [&](int kh, int iw)->float{
      return (rv[kh] && iw < 56) ? rp[kh][iw*192] : 0.f;
    };
    int ow0 = strip*14;
    float xp[3];
#pragma unroll
    for(int kh=0;kh<3;kh++) xp[kh] = ldc(kh, 2*ow0);
    float ksum=0.f, ksq=0.f, vsum=0.f, vsq=0.f;
    size_t orow = ((size_t)b*784 + (size_t)oh*28)*192;
#pragma unroll 1
    for(int j=0;j<14;j++){
      int ow = ow0 + j;
      float xm[3], xn[3];
#pragma unroll
      for(int kh=0;kh<3;kh++){ xm[kh] = ldc(kh, 2*ow+1); xn[kh] = ldc(kh, 2*ow+2); }
      float ak = 0.f, av = 0.f;
#pragma unroll
      for(int kh=0;kh<3;kh++){
        ak = fmaf(xp[kh], wkr[kh*3+0], ak); ak = fmaf(xm[kh], wkr[kh*3+1], ak); ak = fmaf(xn[kh], wkr[kh*3+2], ak);
        av = fmaf(xp[kh], wvr[kh*3+0], av); av = fmaf(xm[kh], wvr[kh*3+1], av); av = fmaf(xn[kh], wvr[kh*3+2], av);
      }
      dkb[orow + (size_t)ow*192 + c] = f2bf(ak);
      dvb[orow + (size_t)ow*192 + c] = f2bf(av);
      ksum += ak; ksq = fmaf(ak, ak, ksq);
      vsum += av; vsq = fmaf(av, av, vsq);
#pragma unroll
      for(int kh=0;kh<3;kh++) xp[kh] = xn[kh];
    }
    red[0][t]=ksum; red[1][t]=ksq; red[2][t]=vsum; red[3][t]=vsq;
    __syncthreads();
    if(t < 192){
      float2 a; a.x = ksum + red[0][t+192]; a.y = ksq + red[1][t+192];
      partk[(size_t)bid*192 + t] = a;
      float2 o; o.x = vsum + red[2][t+192]; o.y = vsq + red[3][t+192];
      partv[(size_t)bid*192 + t] = o;
    }
  }
}

// ---------------- stage-1 reduce of stats partials ----------------
__global__ __launch_bounds__(192) void k_red(const float2* __restrict__ pq, const float2* __restrict__ pk,
                                             const float2* __restrict__ pv, float2* __restrict__ oq,
                                             float2* __restrict__ ok2, float2* __restrict__ ov2){
  int blk = blockIdx.x, t = threadIdx.x;
  const float2* src; float2* dst;
  if(blk < 8){ src = pq + (size_t)blk*112*192;      dst = oq  + (size_t)blk*192; }
  else if(blk < 12){ src = pk + (size_t)(blk-8)*112*192;  dst = ok2 + (size_t)(blk-8)*192; }
  else { src = pv + (size_t)(blk-12)*112*192; dst = ov2 + (size_t)(blk-12)*192; }
  float s=0.f, q=0.f;
#pragma unroll 8
  for(int i=0;i<112;i++){ float2 v = src[(size_t)i*192 + t]; s += v.x; q += v.y; }
  float2 o; o.x=s; o.y=q; dst[t] = o;
}

// ---------------- finalize stats; fold BN + scale into transposed bf16 weights ----------------
__global__ __launch_bounds__(192) void k_fin(const float2* __restrict__ pq, const float2* __restrict__ pk,
                                             const float2* __restrict__ pv,
                                             const float* __restrict__ sq, const float* __restrict__ oq,
                                             const float* __restrict__ sk, const float* __restrict__ ok,
                                             const float* __restrict__ sv, const float* __restrict__ ov,
                                             const float* __restrict__ pwq, const float* __restrict__ pwk,
                                             const float* __restrict__ pwv, const float* __restrict__ wout,
                                             short* __restrict__ Wt, float* __restrict__ bias){
  int p = blockIdx.x, t = threadIdx.x;
  __shared__ float aS[192], bS[192];
  if(p < 3){
    const float2* part = (p==0)?pq:((p==1)?pk:pv);
    int nb = (p==0)?8:4;
    float N = (p==0)?50176.f:12544.f;
    const float* sc = (p==0)?sq:((p==1)?sk:sv);
    const float* of = (p==0)?oq:((p==1)?ok:ov);
    float s=0.f, q2=0.f;
#pragma unroll
    for(int i=0;i<8;i++){ if(i<nb){ float2 v = part[(size_t)i*192 + t]; s += v.x; q2 += v.y; } }
    float mean = s / N;
    float var  = q2 / N - mean*mean;
    float a  = rsqrtf(var + 1e-5f) * sc[t];
    float bv = of[t] - mean*a;
    aS[t] = a; bS[t] = bv;
    __syncthreads();
    const float* pw = (p==0)?pwq:((p==1)?pwk:pwv);
    float qs = (p==0) ? 0.125f : 1.0f;   // fold 1/sqrt(64) into q
    float bacc = 0.f;
    for(int cc=0; cc<192; cc++){
      float wv_ = pw[cc*192 + t];
      bacc = fmaf(bS[cc], wv_, bacc);
      Wt[((size_t)p*192 + t)*192 + cc] = f2bf(aS[cc]*wv_*qs);
    }
    bias[p*192 + t] = bacc * qs;
  } else {
    for(int cc=0; cc<192; cc++) Wt[((size_t)3*192 + t)*192 + cc] = f2bf(wout[cc*192 + t]);
    bias[3*192 + t] = 0.f;
  }
}

// ---------------- K/V pointwise GEMM writing DMA-ready tiled layouts ----------------
// K tile t (32 k-rows): [chunk c24][row r32][8 shorts] -> elem(r,col) at c*256+r*8+(col&7), c=col>>3
// V tile t: [kchunk kc4][col192][8 shorts] -> elem(col,kk) at kc*1536+col*8+(kk&7), kc=(kk&31)>>3
__global__ __launch_bounds__(256) void k_kv(const short* __restrict__ dkb, const short* __restrict__ dvb,
                                            const short* __restrict__ Wt, const float* __restrict__ bias,
                                            short* __restrict__ kbuf, short* __restrict__ vtb){
  int blk = blockIdx.x;
  bool isV = blk >= 208;
  int pb = isV ? blk - 208 : blk;
  int w = threadIdx.x >> 6, L = threadIdx.x & 63, l16 = L & 15, h4 = L >> 4;
  int row0 = pb*64 + w*16;
  int b = row0 / 832, kk0 = row0 - b*832;
  const short* A = isV ? dvb : dkb;
  const short* Wp = Wt + (isV ? 2 : 1)*36864;
  const float* bp = bias + (isV ? 2 : 1)*192;
  int kkA = kk0 + l16; if(kkA > 783) kkA = 783;
  short8 af[6];
  const short8* arow = (const short8*)(A + (size_t)(b*784 + kkA)*192);
#pragma unroll
  for(int kf=0;kf<6;kf++) af[kf] = arow[kf*4 + h4];
  short* obase = (isV ? vtb : kbuf) + (size_t)b*26*6144;
#pragma unroll
  for(int nt=0;nt<12;nt++){
    f32x4 acc = f32x4{0.f,0.f,0.f,0.f};
    const short8* wrow = (const short8*)(Wp + (size_t)(nt*16 + l16)*192);
#pragma unroll
    for(int kf=0;kf<6;kf++)
      acc = __builtin_amdgcn_mfma_f32_16x16x32_bf16(af[kf], wrow[kf*4 + h4], acc, 0,0,0);
    int col = nt*16 + l16;
    float bv = bp[col];
#pragma unroll
    for(int r=0;r<4;r++){
      int kk = kk0 + h4*4 + r;
      float v = (kk < 784) ? (acc[r] + bv) : 0.f;
      int t = kk >> 5, rr = kk & 31;
      if(!isV) obase[(size_t)t*6144 + (col>>3)*256 + rr*8 + (col&7)] = f2bf(v);
      else     obase[(size_t)t*6144 + (rr>>3)*1536 + col*8 + (rr&7)] = f2bf(v);
    }
  }
}

// ---------------- fused single-pass talking-heads attention (R7 structure: best measured) ----------------
// DMA K dbuf + V tribuf, swapped QK (k-contiguous P), cvt_pk pack, exp2 fold, static tail,
// PV software-piped one tile behind QK. One barrier per iteration.
__global__ __launch_bounds__(256, 2) void k_attn(const short* __restrict__ dq, const short* __restrict__ Wt,
                                                 const float* __restrict__ bias,
                                                 const short* __restrict__ kb, const short* __restrict__ vt,
                                                 const float* __restrict__ pre, const float* __restrict__ post,
                                                 float* __restrict__ outp){
  __shared__ __align__(16) short sS[38400];   // 76800 B: K dbuf 12288sh | V tribuf 18432sh | sP 7680sh
  short* sKb = sS;              // 2 x 6144
  short* sVb = sS + 12288;      // 3 x 6144
  short* sP  = sS + 30720;      // [4 w][3 g][16 q][40]
  int bid = blockIdx.x;
  int b  = ((bid & 7) << 1) | ((bid >> 3) & 1);   // XCD-aware: 2 b's per XCD
  int lt = bid >> 4;
  int tid = threadIdx.x; int w = tid >> 6, lane = tid & 63, l16 = lane & 15, h4 = lane >> 4;
  int lw = lt*64 + w*16;
  short* sScr = sS + w*3200;    // per-wave [16][200] prologue/epilogue scratch (barriered overlap)

  // ---- prologue: q = dq @ WtQ^T + biasQ (BN + 1/8 folded), transpose via LDS ----
  {
    short8 af[6];
    const short8* arow = (const short8*)(dq + ((size_t)b*3136 + lw + l16)*192);
#pragma unroll
    for(int kf=0;kf<6;kf++) af[kf] = arow[kf*4 + h4];
#pragma unroll
    for(int nt=0;nt<12;nt++){
      f32x4 acc = f32x4{0.f,0.f,0.f,0.f};
      const short8* wrow = (const short8*)(Wt + (size_t)(nt*16 + l16)*192);
#pragma unroll
      for(int kf=0;kf<6;kf++)
        acc = __builtin_amdgcn_mfma_f32_16x16x32_bf16(af[kf], wrow[kf*4 + h4], acc, 0,0,0);
      float bv = bias[nt*16 + l16];
#pragma unroll
      for(int r=0;r<4;r++) sScr[(h4*4+r)*200 + nt*16 + l16] = f2bf(acc[r] + bv);
    }
  }
  short8 qf[3][2];
#pragma unroll
  for(int h=0;h<3;h++)
#pragma unroll
    for(int kf=0;kf<2;kf++) qf[h][kf] = *(const short8*)&sScr[l16*200 + h*64 + kf*32 + h4*8];

  float pm[3][3];
#pragma unroll
  for(int h=0;h<3;h++)
#pragma unroll
    for(int g=0;g<3;g++) pm[h][g] = sget(pre[h*3+g]) * 1.44269504f;   // fold log2(e): exp->exp2

  f32x4 T[3][3][4];
#pragma unroll
  for(int g=0;g<3;g++)
#pragma unroll
    for(int gp=0;gp<3;gp++)
#pragma unroll
      for(int nt=0;nt<4;nt++) T[g][gp][nt] = f32x4{0.f,0.f,0.f,0.f};
  float Zp[3] = {0.f, 0.f, 0.f};

  const short* kgb = kb + (size_t)b*26*6144;
  const short* vgb = vt + (size_t)b*26*6144;
  int soff = w*1536;            // wave's slice of a 6144-short tile

  auto stage = [&](int t){
    short* kl = sKb + (t&1)*6144 + soff;
    short* vl = sVb + (t%3)*6144 + soff;
    const short* kg = kgb + (size_t)t*6144 + soff + lane*8;
    const short* vg = vgb + (size_t)t*6144 + soff + lane*8;
#pragma unroll
    for(int j=0;j<3;j++){
      async_cp16(kl + j*512, kg + j*512);
      async_cp16(vl + j*512, vg + j*512);
    }
  };

  __syncthreads();              // prologue scratch reads done before DMA lands
  stage(0);
  __syncthreads();              // vmcnt drained: tile 0 ready

  int sPw = w*1920;
#pragma unroll 1
  for(int ks=0; ks<25; ks++){
    if(ks < 24) stage(ks+1);
    const short* sKc = sKb + (ks&1)*6144;
    // ---- QK (swapped: A=K rows -> C[col=q=l16][row=k=h4*4+r]) ----
    f32x4 acc[3][2];
#pragma unroll
    for(int h=0;h<3;h++)
#pragma unroll
      for(int nt=0;nt<2;nt++) acc[h][nt] = f32x4{0.f,0.f,0.f,0.f};
#pragma unroll
    for(int h=0;h<3;h++)
#pragma unroll
      for(int kf=0;kf<2;kf++){
        short8 aq = qf[h][kf];
#pragma unroll
        for(int nt=0;nt<2;nt++){
          short8 bk = *(const short8*)&sKc[(h*8 + kf*4 + h4)*256 + (nt*16 + l16)*8];
          acc[h][nt] = __builtin_amdgcn_mfma_f32_16x16x32_bf16(bk, aq, acc[h][nt], 0,0,0);
        }
      }
    // ---- PV of previous tile (software pipe; sP read-before-write, in-order DS) ----
    if(ks){
      const short* sVp = sVb + ((ks-1)%3)*6144 + h4*1536;
      short8 pa[3];
#pragma unroll
      for(int g=0;g<3;g++) pa[g] = *(const short8*)&sP[sPw + g*640 + l16*40 + h4*8];
#pragma unroll
      for(int gp=0;gp<3;gp++)
#pragma unroll
        for(int nt=0;nt<4;nt++){
          short8 vb = *(const short8*)(sVp + (gp*64 + nt*16 + l16)*8);
#pragma unroll
          for(int g=0;g<3;g++)
            T[g][gp][nt] = __builtin_amdgcn_mfma_f32_16x16x32_bf16(pa[g], vb, T[g][gp][nt], 0,0,0);
        }
    }
    // ---- premix + exp2 -> packed bf16 P -> sP (k-contiguous pairs) ----
#pragma unroll
    for(int nt=0;nt<2;nt++){
      bool zok = (ks < 24) || (nt == 0);        // static tail: only (ks==24,nt==1) invalid
#pragma unroll
      for(int g=0;g<3;g++){
        float e[4];
#pragma unroll
        for(int r=0;r<4;r++){
          float sm = fmaf(pm[0][g], acc[0][nt][r], fmaf(pm[1][g], acc[1][nt][r], pm[2][g]*acc[2][nt][r]));
          e[r] = exp2f(sm);
        }
        if(zok) Zp[g] += (e[0] + e[1]) + (e[2] + e[3]);
        uint2 dw; dw.x = cvtpk_bf16(e[0], e[1]); dw.y = cvtpk_bf16(e[2], e[3]);
        *(uint2*)&sP[sPw + g*640 + l16*40 + nt*16 + h4*4] = dw;
      }
    }
    __syncthreads();            // DMAs landed; all waves done with sK[ks&1] and sV[(ks-1)%3]
  }
  // ---- drain: PV of last tile (24), V slot 24%3 = 0 ----
  {
    const short* sVp = sVb + (24%3)*6144 + h4*1536;
    short8 pa[3];
#pragma unroll
    for(int g=0;g<3;g++) pa[g] = *(const short8*)&sP[sPw + g*640 + l16*40 + h4*8];
#pragma unroll
    for(int gp=0;gp<3;gp++)
#pragma unroll
      for(int nt=0;nt<4;nt++){
        short8 vb = *(const short8*)(sVp + (gp*64 + nt*16 + l16)*8);
#pragma unroll
        for(int g=0;g<3;g++)
          T[g][gp][nt] = __builtin_amdgcn_mfma_f32_16x16x32_bf16(pa[g], vb, T[g][gp][nt], 0,0,0);
      }
  }

  // ---- Z: reduce across h4 groups (lanes +-16, +-32); redistribute to T's row-q ----
  float izq[3][4];
#pragma unroll
  for(int g=0;g<3;g++){
    float z = Zp[g];
    z += __shfl_xor(z, 16); z += __shfl_xor(z, 32);
    float iz = 1.f / z;                          // invZ for q = l16
#pragma unroll
    for(int r=0;r<4;r++) izq[g][r] = __shfl(iz, h4*4 + r);   // invZ for q = h4*4+r
  }
  float po[3][3];
#pragma unroll
  for(int g=0;g<3;g++)
#pragma unroll
    for(int gp=0;gp<3;gp++) po[g][gp] = sget(post[g*3+gp]);

  // ---- epilogue: mix T -> bf16 scratch, then @ Wout, write f32 ----
#pragma unroll
  for(int gp=0;gp<3;gp++){
    float cg[3][4];
#pragma unroll
    for(int g=0;g<3;g++)
#pragma unroll
      for(int r=0;r<4;r++) cg[g][r] = po[g][gp] * izq[g][r];
#pragma unroll
    for(int nt=0;nt<4;nt++){
#pragma unroll
      for(int r=0;r<4;r++){
        float u = fmaf(cg[0][r], T[0][gp][nt][r], fmaf(cg[1][r], T[1][gp][nt][r], cg[2][r]*T[2][gp][nt][r]));
        sScr[(h4*4+r)*200 + gp*64 + nt*16 + l16] = f2bf(u);
      }
    }
  }
  short8 uf[6];
#pragma unroll
  for(int kf=0;kf<6;kf++) uf[kf] = *(const short8*)&sScr[l16*200 + kf*32 + h4*8];
  const short* W3 = Wt + 3*36864;
#pragma unroll
  for(int nt=0;nt<12;nt++){
    f32x4 acc = f32x4{0.f,0.f,0.f,0.f};
    const short8* wrow = (const short8*)(W3 + (size_t)(nt*16 + l16)*192);
#pragma unroll
    for(int kf=0;kf<6;kf++)
      acc = __builtin_amdgcn_mfma_f32_16x16x32_bf16(uf[kf], wrow[kf*4 + h4], acc, 0,0,0);
#pragma unroll
    for(int r=0;r<4;r++)
      outp[((size_t)b*3136 + lw + h4*4 + r)*192 + nt*16 + l16] = acc[r];
  }
}

extern "C" void kernel_launch(void* const* d_in, const int* in_sizes, int n_in,
                              void* d_out, int out_size, void* d_ws, size_t ws_size,
                              hipStream_t stream){
  (void)in_sizes; (void)n_in; (void)out_size; (void)ws_size;
  const float* inq  = (const float*)d_in[0];
  const float* inkv = (const float*)d_in[1];
  const float* dwq  = (const float*)d_in[2];
  const float* dwk  = (const float*)d_in[3];
  const float* dwv  = (const float*)d_in[4];
  const float* scq  = (const float*)d_in[5];  const float* ofq = (const float*)d_in[6];
  const float* sck  = (const float*)d_in[7];  const float* ofk = (const float*)d_in[8];
  const float* scv  = (const float*)d_in[9];  const float* ofv = (const float*)d_in[10];
  const float* pwq  = (const float*)d_in[11];
  const float* pwk  = (const float*)d_in[12];
  const float* pwv  = (const float*)d_in[13];
  const float* pre  = (const float*)d_in[14];
  const float* post = (const float*)d_in[15];
  const float* wout = (const float*)d_in[16];

  char* ws = (char*)d_ws;
  size_t off = 0;
  auto alloc = [&](size_t bytes)->void*{ void* p = ws + off; off += (bytes + 255) & ~(size_t)255; return p; };
  short*  dqb  = (short*) alloc(50176ull*192*2);
  short*  dkb  = (short*) alloc(12544ull*192*2);
  short*  dvb  = (short*) alloc(12544ull*192*2);
  short*  kbuf = (short*) alloc(16ull*26*6144*2);
  short*  vtb  = (short*) alloc(16ull*26*6144*2);
  float2* pq   = (float2*)alloc(896ull*192*sizeof(float2));
  float2* pk   = (float2*)alloc(448ull*192*sizeof(float2));
  float2* pv   = (float2*)alloc(448ull*192*sizeof(float2));
  float2* pq2  = (float2*)alloc(8ull*192*sizeof(float2));
  float2* pk2  = (float2*)alloc(4ull*192*sizeof(float2));
  float2* pv2  = (float2*)alloc(4ull*192*sizeof(float2));
  short*  Wt   = (short*) alloc(4ull*192*192*2);
  float*  bias = (float*) alloc(4ull*192*4);

  k_dw<<<1344, 384, 0, stream>>>(inq, inkv, dwq, dwk, dwv, dqb, dkb, dvb, pq, pk, pv);
  k_red<<<16, 192, 0, stream>>>(pq, pk, pv, pq2, pk2, pv2);
  k_fin<<<4, 192, 0, stream>>>(pq2, pk2, pv2, scq, ofq, sck, ofk, scv, ofv, pwq, pwk, pwv, wout, Wt, bias);
  k_kv<<<416, 256, 0, stream>>>(dkb, dvb, Wt, bias, kbuf, vtb);
  k_attn<<<784, 256, 0, stream>>>(dqb, Wt, bias, kbuf, vtb, pre, post, (float*)d_out);
}